// Round 6
// baseline (126.216 us; speedup 1.0000x reference)
//
#include <hip/hip_runtime.h>
#include <hip/hip_bf16.h>

// SoftRAM attention: S=128, B=256 bits, H=16 heads, NB=12 bits/neuron, PB=7.
// addr(i,j,h,n) = aq[i] + ak[j] + ap[i-j] (disjoint bit groups per (h,n));
// only sign(memory) matters.
//
// R6: LDS-pipe throughput fix (R5 was 13K ds-instr/CU + stride-8 conflicts).
// Ballot scheme: lane = key j (slots j=lane, j+64); wave-uniform i loop.
//  - ak: per-lane register (0 LDS reads)
//  - aq: one b128 broadcast per 8 i's
//  - ap: read only for heads with position bits (~15% of heads)
//  - causal parity: __ballot + scalar popcount with prefix masks (no per-lane
//    j/rel index math, no accumulator selects)
// LUT: direct f32 sign test on the async-staged rows (no byte-LUT, no pack).
// ~1.2 ds-reads per lookup vs R5's 3, conflict-free except the random lut read.

#define S 128
#define B 256
#define H 16
#define NB 12

typedef __attribute__((address_space(3))) void       lds_void;
typedef const __attribute__((address_space(1))) void glb_void;

__device__ __forceinline__ void async16(const float* g, float* l) {
    __builtin_amdgcn_global_load_lds((glb_void*)g, (lds_void*)l, 16, 0, 0);
}

__global__ __launch_bounds__(1024) void softram_kernel(
    const int* __restrict__ tokens,        // [S,B] 0/1
    const float* __restrict__ memory,      // [H,B,4096]
    const int* __restrict__ connections,   // [H,B,NB]
    int* __restrict__ out)                 // [S,B] 0/1
{
    const int n    = blockIdx.x;
    const int tid  = threadIdx.x;
    const int wv   = tid >> 6;
    const int lane = tid & 63;

    __shared__ float          raw[2][2][4096];     // [buf][head-of-pair][idx] 64KB
    __shared__ unsigned int   tok[S * 8];          // 4 KB packed token bits
    __shared__ unsigned short aqs[H][S];           // 4 KB
    __shared__ unsigned short aks[H][S];           // 4 KB
    __shared__ unsigned short aps[H][S];           // 4 KB
    __shared__ int            conns[H][NB];        // 768 B
    __shared__ int            hasP[H];
    __shared__ unsigned char  partsA[H][8];        // parity bits, i<64 (q,t)
    __shared__ unsigned char  partsB[H][8];        // parity bits, i>=64

    // Stage round r (heads 2r, 2r+1 -> 32 KB) into raw[buf]. 32 chunks of 1 KB;
    // wave issues 2 chunks; lds dest = uniform base + lane*16 (HW rule).
    auto issue_round = [&](int r, int buf) {
        #pragma unroll
        for (int q2 = 0; q2 < 2; ++q2) {
            int c = wv * 2 + q2;                   // 0..31
            const float* g = memory + ((size_t)((2 * r + (c >> 4)) * 256 + n) << 12)
                           + ((c & 15) << 8) + (lane << 2);
            float* l = &raw[buf][c >> 4][(c & 15) << 8];
            async16(g, l);
        }
    };

    // ---- Preamble ----
    issue_round(0, 0);
    {   // token bit-pack: thread -> one dword (32 token bits)
        int i = tid >> 3, w = tid & 7;
        const int4* tp = (const int4*)tokens;
        unsigned int t = 0;
        #pragma unroll
        for (int u = 0; u < 8; ++u) {
            int4 x = tp[i * 64 + w * 8 + u];
            t |= (unsigned)(x.x & 1) << (4 * u + 0);
            t |= (unsigned)(x.y & 1) << (4 * u + 1);
            t |= (unsigned)(x.z & 1) << (4 * u + 2);
            t |= (unsigned)(x.w & 1) << (4 * u + 3);
        }
        tok[tid] = t;
    }
    if (tid < H * NB) {
        int h = tid / NB, b = tid - h * NB;
        conns[h][b] = connections[h * (B * NB) + n * NB + b];
    }
    __syncthreads();                 // raw[0] drained; tok, conns visible

    issue_round(1, 1);

    if (tid < H) {
        int f = 0;
        #pragma unroll
        for (int b = 0; b < NB; ++b) f |= (conns[tid][b] >= 512);
        hasP[tid] = f;
    }
    // Tables for all 16 heads (2 entries/thread; h wave-uniform -> uniform br).
    #pragma unroll
    for (int e0 = 0; e0 < 2; ++e0) {
        int e = tid + (e0 << 10);
        int h = e >> 7, ii = e & 127;
        unsigned aq = 0, ak = 0, ap = 0;
        #pragma unroll
        for (int b = 0; b < NB; ++b) {
            int c = conns[h][b];
            if (c < 256) {
                aq |= ((tok[ii * 8 + (c >> 5)] >> (c & 31)) & 1u) << b;
            } else if (c < 512) {
                int c2 = c - 256;
                ak |= ((tok[ii * 8 + (c2 >> 5)] >> (c2 & 31)) & 1u) << b;
            } else {
                ap |= (unsigned)((ii >> (c - 512)) & 1) << b;
            }
        }
        aqs[h][ii] = (unsigned short)aq;
        aks[h][ii] = (unsigned short)ak;
        aps[h][ii] = (unsigned short)ap;
    }
    __syncthreads();                 // raw[1] drained; tables + hasP visible

    // ---- Pipelined rounds: wave = (head-of-pair hh, i-block q) ----
    const int hh = wv & 1;
    const int q  = wv >> 1;          // 0..7
    for (int r = 0; r < 8; ++r) {
        if (r < 7) issue_round(r + 1, (r + 1) & 1);   // overlaps D below

        const int h = 2 * r + hh;
        const float* __restrict__ lrow = &raw[r & 1][hh][0];
        const unsigned ak0 = aks[h][lane];
        const unsigned ak1 = aks[h][lane + 64];
        const bool hp = (hasP[h] != 0);               // wave-uniform
        unsigned accA = 0, accB = 0;

        {   // low i-block: i = q*8 + t  (i < 64; only keys j = lane active)
            uint4 aqw = *(const uint4*)&aqs[h][q * 8];
            const unsigned short* aqp = (const unsigned short*)&aqw;
            #pragma unroll
            for (int t = 0; t < 8; ++t) {
                int i = q * 8 + t;
                unsigned ap0 = hp ? (unsigned)aps[h][(i - lane) & 127] : 0u;
                float v0 = lrow[aqp[t] + ak0 + ap0];
                unsigned long long m0 = __ballot(v0 > 0.0f);
                unsigned long long c0 = (2ull << i) - 1;     // lanes j<=i
                accA |= (unsigned)(__popcll(m0 & c0) & 1) << t;
            }
        }
        {   // high i-block: i = 64 + q*8 + t (all j=lane active, j=lane+64 prefix)
            uint4 aqw = *(const uint4*)&aqs[h][64 + q * 8];
            const unsigned short* aqp = (const unsigned short*)&aqw;
            #pragma unroll
            for (int t = 0; t < 8; ++t) {
                int i = 64 + q * 8 + t;
                unsigned ap0 = 0, ap1 = 0;
                if (hp) {
                    ap0 = aps[h][(i - lane) & 127];
                    ap1 = aps[h][(i - lane - 64) & 127];
                }
                float v0 = lrow[aqp[t] + ak0 + ap0];
                float v1 = lrow[aqp[t] + ak1 + ap1];
                unsigned long long m0 = __ballot(v0 > 0.0f);
                unsigned long long m1 = __ballot(v1 > 0.0f);
                unsigned long long c1 = (2ull << (i - 64)) - 1;  // lanes j-64<=i-64
                accB |= (unsigned)((__popcll(m0) + __popcll(m1 & c1)) & 1) << t;
            }
        }
        if (lane == 0) {
            partsA[h][q] = (unsigned char)accA;
            partsB[h][q] = (unsigned char)accB;
        }
        __syncthreads();             // D(r) done; issue(r+1) drained
    }

    // ---- Epilogue: majority vote across 16 heads ----
    if (tid < S) {
        int i = tid;
        int tot = 0;
        #pragma unroll
        for (int h2 = 0; h2 < H; ++h2) {
            unsigned bits = (i < 64) ? partsA[h2][i >> 3] : partsB[h2][(i - 64) >> 3];
            tot += (bits >> (i & 7)) & 1;
        }
        out[i * B + n] = (tot > (H / 2)) ? 1 : 0;
    }
}

extern "C" void kernel_launch(void* const* d_in, const int* in_sizes, int n_in,
                              void* d_out, int out_size, void* d_ws, size_t ws_size,
                              hipStream_t stream) {
    const int*   tokens      = (const int*)d_in[0];
    const float* memory      = (const float*)d_in[1];
    const int*   connections = (const int*)d_in[2];
    int*         out         = (int*)d_out;
    (void)in_sizes; (void)n_in; (void)out_size; (void)d_ws; (void)ws_size;

    softram_kernel<<<B, 1024, 0, stream>>>(tokens, memory, connections, out);
}

// Round 7
// 114.187 us; speedup vs baseline: 1.1053x; 1.1053x over previous
//
#include <hip/hip_runtime.h>
#include <hip/hip_bf16.h>

// SoftRAM attention: S=128, B=256 bits, H=16 heads, NB=12 bits/neuron, PB=7.
// addr(i,j,h,n) = aq_i | ak_j | ap_{i-j}, disjoint bit groups per (h,n).
//
// R7: conflict-free subspace scheme. Per head, lanes enumerate the SMALLER of
// the q/k bit-subspaces (min(qb,kb) <= 6 always since qb+kb <= 12), sweeping
// the other dimension with per-lane prefix parity; causality via ballot +
// scalar popcount. Byte-LUT stored under GF2-linear swizzle
// sigma(p) = p ^ ((p>>3)&0x70) ^ ((p>>6)&0x70)  (preserves bits 0-3, folds
// high bits into banks; sigma(x|y) = sigma(x)^sigma(y) for disjoint x,y).
// Wave w owns head w end-to-end (stage -> pack -> sweep) with per-wave vmcnt
// only; 2 block barriers total. Heads with position bits use a direct
// per-lane-j fallback on the same sigma-table.

#define S 128
#define B 256
#define H 16
#define NB 12

__device__ __forceinline__ unsigned sig(unsigned x) {
    return x ^ ((x >> 3) & 0x70u) ^ ((x >> 6) & 0x70u);
}

__global__ __launch_bounds__(1024) void softram_kernel(
    const int* __restrict__ tokens,        // [S,B] 0/1
    const float* __restrict__ memory,      // [H,B,4096]
    const int* __restrict__ connections,   // [H,B,NB]
    int* __restrict__ out)                 // [S,B] 0/1
{
    const int n    = blockIdx.x;
    const int tid  = threadIdx.x;
    const int h    = tid >> 6;             // wave == head
    const int lane = tid & 63;

    __shared__ unsigned char  bytetab[H * 4096];   // 64 KB sigma-packed signs
    __shared__ unsigned int   tokT[8][S];          // 4 KB transposed token bits
    __shared__ unsigned short aqsig[H][S];         // 4 KB sigma(aq_val)
    __shared__ unsigned short aksig[H][S];         // 4 KB sigma(ak_val)
    __shared__ unsigned short apsig[H][S];         // 4 KB sigma(ap_val) by dist
    __shared__ int            conns[H][NB];        // 768 B
    __shared__ unsigned int   parts[H][4];         // 128 result bits per head

    // ---- stage issue, first half: 8 coalesced b128 loads of head h's row ----
    const float4* mrow = (const float4*)(memory + ((size_t)(h * 256 + n) << 12));
    float4 va[8];
    #pragma unroll
    for (int t = 0; t < 8; ++t) va[t] = mrow[lane + 64 * t];

    // ---- token pack (transposed: tokT[w][i]) ----
    {
        int i = tid >> 3, w = tid & 7;
        const int4* tp = (const int4*)tokens;
        unsigned v = 0;
        #pragma unroll
        for (int u = 0; u < 8; ++u) {
            int4 x = tp[i * 64 + w * 8 + u];
            v |= (unsigned)(x.x & 1) << (4 * u + 0);
            v |= (unsigned)(x.y & 1) << (4 * u + 1);
            v |= (unsigned)(x.z & 1) << (4 * u + 2);
            v |= (unsigned)(x.w & 1) << (4 * u + 3);
        }
        tokT[w][i] = v;
    }
    if (tid < H * NB) {
        int hh = tid / NB, b = tid - hh * NB;
        conns[hh][b] = connections[hh * (B * NB) + n * NB + b];
    }

    // second half of stage loads
    float4 vb[8];
    #pragma unroll
    for (int t = 0; t < 8; ++t) vb[t] = mrow[lane + 64 * (t + 8)];

    __syncthreads();                 // tokT + conns visible (drains loads too)

    // ---- per-head masks (wave-uniform) ----
    unsigned qmask = 0, kmask = 0, pmask = 0;
    #pragma unroll
    for (int b = 0; b < NB; ++b) {
        int c = conns[h][b];
        qmask |= (unsigned)(c < 256) << b;
        kmask |= (unsigned)(c >= 256 && c < 512) << b;
        pmask |= (unsigned)(c >= 512) << b;
    }

    // ---- pack signs into sigma-addressed bytes (own head's region) ----
    unsigned char* __restrict__ bt = &bytetab[h << 12];
    #pragma unroll
    for (int t = 0; t < 16; ++t) {
        float4 v = (t < 8) ? va[t] : vb[t - 8];
        unsigned p = 4u * (unsigned)(lane + 64 * t);
        unsigned w = (unsigned)(v.x > 0.f)
                   | ((unsigned)(v.y > 0.f) << 8)
                   | ((unsigned)(v.z > 0.f) << 16)
                   | ((unsigned)(v.w > 0.f) << 24);
        *(unsigned*)&bt[sig(p)] = w;   // sigma keeps bits 0-3 -> aligned, consecutive
    }

    // ---- per-head tables: sigma(aq), sigma(ak), sigma(ap). 2 entries/lane ----
    #pragma unroll
    for (int e = 0; e < 2; ++e) {
        int ii = lane + 64 * e;
        unsigned aq = 0, ak = 0, ap = 0;
        #pragma unroll
        for (int b = 0; b < NB; ++b) {
            int c = conns[h][b];       // wave-uniform -> uniform branches
            if (c < 256) {
                aq |= ((tokT[c >> 5][ii] >> (c & 31)) & 1u) << b;
            } else if (c < 512) {
                int c2 = c - 256;
                ak |= ((tokT[c2 >> 5][ii] >> (c2 & 31)) & 1u) << b;
            } else {
                ap |= ((unsigned)(ii >> (c - 512)) & 1u) << b;
            }
        }
        aqsig[h][ii] = (unsigned short)sig(aq);
        aksig[h][ii] = (unsigned short)sig(ak);
        apsig[h][ii] = (unsigned short)sig(ap);
    }

    // ---- Phase D: per-wave sweep, results in two scalar u64 ----
    unsigned long long rlo = 0, rhi = 0;

    if (pmask == 0) {
        // fast path: lanes = smaller subspace, sweep the other dimension
        int qb = __popc(qmask), kb = __popc(kmask);
        bool sideQ = (qb <= kb);
        unsigned smask = sideQ ? qmask : kmask;
        int m = sideQ ? qb : kb;                   // <= 6 always
        // spread = pdep(lane, smask), then sigma
        unsigned spread = 0;
        {
            unsigned k = (unsigned)lane;
            #pragma unroll
            for (int b = 0; b < NB; ++b) {
                if ((smask >> b) & 1u) { spread |= (k & 1u) << b; k >>= 1; }
            }
        }
        const unsigned spv = sig(spread);
        const int lim = 1 << m;
        const bool lv = (lane < lim);
        const unsigned long long vmask =
            (lim >= 64) ? ~0ull : ((1ull << lim) - 1ull);

        if (sideQ) {
            // lanes = Q-subspace; sweep keys j; acc = running XOR per lane;
            // capture result for query i=j at the lane matching aq_i.
            unsigned acc = 0;
            for (int s8 = 0; s8 < 16; ++s8) {
                uint4 uq = *(const uint4*)&aqsig[h][s8 * 8];
                uint4 uk = *(const uint4*)&aksig[h][s8 * 8];
                #pragma unroll
                for (int t = 0; t < 8; ++t) {
                    int j = s8 * 8 + t;
                    unsigned cwk = ((const unsigned*)&uk)[t >> 1];
                    unsigned cwq = ((const unsigned*)&uq)[t >> 1];
                    unsigned akv = (cwk >> ((t & 1) * 16)) & 0xffffu;
                    unsigned aqv = (cwq >> ((t & 1) * 16)) & 0xffffu;
                    acc ^= bt[akv ^ spv];
                    unsigned long long accB = __ballot((acc & 1u) != 0u);
                    unsigned long long mm   = __ballot(lv && (spv == aqv));
                    unsigned long long bit  = ((accB & mm & vmask) != 0ull);
                    if (j < 64) rlo |= bit << j; else rhi |= bit << (j - 64);
                }
            }
        } else {
            // lanes = K-subspace; sweep queries i; c = prefix parity of keys
            // in this lane's class; result_i = parity(sum_lane c * s-bit).
            unsigned c = 0;
            for (int s8 = 0; s8 < 16; ++s8) {
                uint4 uq = *(const uint4*)&aqsig[h][s8 * 8];
                uint4 uk = *(const uint4*)&aksig[h][s8 * 8];
                #pragma unroll
                for (int t = 0; t < 8; ++t) {
                    int i = s8 * 8 + t;
                    unsigned cwk = ((const unsigned*)&uk)[t >> 1];
                    unsigned cwq = ((const unsigned*)&uq)[t >> 1];
                    unsigned akv = (cwk >> ((t & 1) * 16)) & 0xffffu;
                    unsigned aqv = (cwq >> ((t & 1) * 16)) & 0xffffu;
                    c ^= (unsigned)(lv && (spv == akv));      // include key j=i
                    unsigned sb = bt[aqv ^ spv];
                    unsigned long long mb = __ballot((c & sb & 1u) != 0u);
                    unsigned long long bit = (unsigned long long)
                        (__popcll(mb & vmask) & 1ull);
                    if (i < 64) rlo |= bit << i; else rhi |= bit << (i - 64);
                }
            }
        }
    } else {
        // P fallback: lane = key j (and j+64); sweep queries i directly.
        const unsigned ak0 = aksig[h][lane];
        const unsigned ak1 = aksig[h][lane + 64];
        for (int s8 = 0; s8 < 16; ++s8) {
            uint4 uq = *(const uint4*)&aqsig[h][s8 * 8];
            #pragma unroll
            for (int t = 0; t < 8; ++t) {
                int i = s8 * 8 + t;
                unsigned cwq = ((const unsigned*)&uq)[t >> 1];
                unsigned aqv = (cwq >> ((t & 1) * 16)) & 0xffffu;
                unsigned ap0 = apsig[h][(i - lane) & 127];
                unsigned v0  = bt[aqv ^ ak0 ^ ap0];
                unsigned long long m0 = __ballot((v0 & 1u) != 0u);
                unsigned long long pre0 =
                    (i >= 63) ? ~0ull : ((2ull << i) - 1ull);
                unsigned cnt = (unsigned)__popcll(m0 & pre0);
                if (i >= 64) {
                    unsigned ap1 = apsig[h][(i - lane - 64) & 127];
                    unsigned v1  = bt[aqv ^ ak1 ^ ap1];
                    unsigned long long m1 = __ballot((v1 & 1u) != 0u);
                    unsigned long long pre1 =
                        (i >= 127) ? ~0ull : ((2ull << (i - 64)) - 1ull);
                    cnt += (unsigned)__popcll(m1 & pre1);
                }
                unsigned long long bit = cnt & 1u;
                if (i < 64) rlo |= bit << i; else rhi |= bit << (i - 64);
            }
        }
    }

    if (lane == 0) {
        parts[h][0] = (unsigned)rlo;
        parts[h][1] = (unsigned)(rlo >> 32);
        parts[h][2] = (unsigned)rhi;
        parts[h][3] = (unsigned)(rhi >> 32);
    }
    __syncthreads();

    // ---- majority vote across 16 heads ----
    if (tid < S) {
        int i = tid, tot = 0;
        #pragma unroll
        for (int hh = 0; hh < H; ++hh)
            tot += (parts[hh][i >> 5] >> (i & 31)) & 1;
        out[i * B + n] = (tot > (H / 2)) ? 1 : 0;
    }
}

extern "C" void kernel_launch(void* const* d_in, const int* in_sizes, int n_in,
                              void* d_out, int out_size, void* d_ws, size_t ws_size,
                              hipStream_t stream) {
    const int*   tokens      = (const int*)d_in[0];
    const float* memory      = (const float*)d_in[1];
    const int*   connections = (const int*)d_in[2];
    int*         out         = (int*)d_out;
    (void)in_sizes; (void)n_in; (void)out_size; (void)d_ws; (void)ws_size;

    softram_kernel<<<B, 1024, 0, stream>>>(tokens, memory, connections, out);
}

// Round 8
// 112.803 us; speedup vs baseline: 1.1189x; 1.0123x over previous
//
#include <hip/hip_runtime.h>
#include <hip/hip_bf16.h>

// SoftRAM attention: S=128, B=256 bits, H=16 heads, NB=12 bits/neuron, PB=7.
// addr(i,j,h,n) = aq_i | ak_j | ap_{i-j}, disjoint bit groups per (h,n).
//
// R8: R7's subspace sweep + sigma swizzle, restructured so the big HBM stage
// is NOT serialized behind a barrier. Order: token-pack -> barrier #1 (drains
// only token reads) -> each wave issues its own head's 16KB loads -> builds
// its own tables (overlaps drain) -> packs its own sigma byte-LUT -> sweeps.
// No barrier between stage and sweep: every LDS object a wave reads post-
// barrier-#1 is written by that same wave (in-order LDS pipe => visible).
// Waves finish staggered; HBM drain overlaps other waves' sweeps.
// Critical path: max(full-drain + fast sweep, own-drain + P-fallback sweep).

#define S 128
#define B 256
#define H 16
#define NB 12

__device__ __forceinline__ unsigned sig(unsigned x) {
    return x ^ ((x >> 3) & 0x70u) ^ ((x >> 6) & 0x70u);
}

__global__ __launch_bounds__(1024) void softram_kernel(
    const int* __restrict__ tokens,        // [S,B] 0/1
    const float* __restrict__ memory,      // [H,B,4096]
    const int* __restrict__ connections,   // [H,B,NB]
    int* __restrict__ out)                 // [S,B] 0/1
{
    const int n    = blockIdx.x;
    const int tid  = threadIdx.x;
    const int h    = tid >> 6;             // wave == head
    const int lane = tid & 63;

    __shared__ unsigned char  bytetab[H * 4096];   // 64 KB sigma-packed signs
    __shared__ unsigned int   tokT[8][S];          // 4 KB transposed token bits
    __shared__ unsigned short aqsig[H][S];         // 4 KB sigma(aq_val)
    __shared__ unsigned short aksig[H][S];         // 4 KB sigma(ak_val)
    __shared__ unsigned short apsig[H][S];         // 4 KB sigma(ap_val) by dist
    __shared__ int            conns[H][NB];        // 768 B
    __shared__ unsigned int   parts[H][4];         // 128 result bits per head

    // ---- token pack (transposed: tokT[w][i]) + conns ----
    {
        int i = tid >> 3, w = tid & 7;
        const int4* tp = (const int4*)tokens;
        unsigned v = 0;
        #pragma unroll
        for (int u = 0; u < 8; ++u) {
            int4 x = tp[i * 64 + w * 8 + u];
            v |= (unsigned)(x.x & 1) << (4 * u + 0);
            v |= (unsigned)(x.y & 1) << (4 * u + 1);
            v |= (unsigned)(x.z & 1) << (4 * u + 2);
            v |= (unsigned)(x.w & 1) << (4 * u + 3);
        }
        tokT[w][i] = v;
    }
    if (tid < H * NB) {
        int hh = tid / NB, b = tid - hh * NB;
        conns[hh][b] = connections[hh * (B * NB) + n * NB + b];
    }
    __syncthreads();   // barrier #1: tokT + conns visible (drains token reads only)

    // ---- issue own head's row loads (16 KB, coalesced b128) ----
    const float4* mrow = (const float4*)(memory + ((size_t)(h * 256 + n) << 12));
    float4 va[16];
    #pragma unroll
    for (int t = 0; t < 16; ++t) va[t] = mrow[lane + 64 * t];

    // ---- per-head masks (wave-uniform; overlaps load drain) ----
    unsigned qmask = 0, kmask = 0, pmask = 0;
    #pragma unroll
    for (int b = 0; b < NB; ++b) {
        int c = conns[h][b];
        qmask |= (unsigned)(c < 256) << b;
        kmask |= (unsigned)(c >= 256 && c < 512) << b;
        pmask |= (unsigned)(c >= 512) << b;
    }

    // ---- per-head tables: sigma(aq), sigma(ak), sigma(ap) (overlaps drain) ----
    #pragma unroll
    for (int e = 0; e < 2; ++e) {
        int ii = lane + 64 * e;
        unsigned aq = 0, ak = 0, ap = 0;
        #pragma unroll
        for (int b = 0; b < NB; ++b) {
            int c = conns[h][b];       // wave-uniform -> uniform branches
            if (c < 256) {
                aq |= ((tokT[c >> 5][ii] >> (c & 31)) & 1u) << b;
            } else if (c < 512) {
                int c2 = c - 256;
                ak |= ((tokT[c2 >> 5][ii] >> (c2 & 31)) & 1u) << b;
            } else {
                ap |= ((unsigned)(ii >> (c - 512)) & 1u) << b;
            }
        }
        aqsig[h][ii] = (unsigned short)sig(aq);
        aksig[h][ii] = (unsigned short)sig(ak);
        apsig[h][ii] = (unsigned short)sig(ap);
    }

    // ---- pack signs into sigma-addressed bytes (own head's region) ----
    unsigned char* __restrict__ bt = &bytetab[h << 12];
    #pragma unroll
    for (int t = 0; t < 16; ++t) {
        float4 v = va[t];
        unsigned p = 4u * (unsigned)(lane + 64 * t);
        unsigned w = (unsigned)(v.x > 0.f)
                   | ((unsigned)(v.y > 0.f) << 8)
                   | ((unsigned)(v.z > 0.f) << 16)
                   | ((unsigned)(v.w > 0.f) << 24);
        *(unsigned*)&bt[sig(p)] = w;   // sigma keeps bits 0-3 -> aligned dword
    }

    // ---- Phase D: per-wave sweep (no barrier needed: all inputs self-written) ----
    unsigned long long rlo = 0, rhi = 0;

    if (pmask == 0) {
        // fast path: lanes = smaller subspace, sweep the other dimension
        int qb = __popc(qmask), kb = __popc(kmask);
        bool sideQ = (qb <= kb);
        unsigned smask = sideQ ? qmask : kmask;
        int m = sideQ ? qb : kb;                   // <= 6 always
        unsigned spread = 0;
        {
            unsigned k = (unsigned)lane;
            #pragma unroll
            for (int b = 0; b < NB; ++b) {
                if ((smask >> b) & 1u) { spread |= (k & 1u) << b; k >>= 1; }
            }
        }
        const unsigned spv = sig(spread);
        const int lim = 1 << m;
        const bool lv = (lane < lim);
        const unsigned long long vmask =
            (lim >= 64) ? ~0ull : ((1ull << lim) - 1ull);

        if (sideQ) {
            // lanes = Q-subspace; sweep keys j; per-lane running parity acc;
            // capture result for query i=j at the lane matching aq_i.
            unsigned acc = 0;
            for (int s8 = 0; s8 < 16; ++s8) {
                uint4 uq = *(const uint4*)&aqsig[h][s8 * 8];
                uint4 uk = *(const uint4*)&aksig[h][s8 * 8];
                #pragma unroll
                for (int t = 0; t < 8; ++t) {
                    int j = s8 * 8 + t;
                    unsigned cwk = ((const unsigned*)&uk)[t >> 1];
                    unsigned cwq = ((const unsigned*)&uq)[t >> 1];
                    unsigned akv = (cwk >> ((t & 1) * 16)) & 0xffffu;
                    unsigned aqv = (cwq >> ((t & 1) * 16)) & 0xffffu;
                    acc ^= bt[akv ^ spv];
                    unsigned long long accB = __ballot((acc & 1u) != 0u);
                    unsigned long long mm   = __ballot(lv && (spv == aqv));
                    unsigned long long bit  = ((accB & mm & vmask) != 0ull);
                    if (j < 64) rlo |= bit << j; else rhi |= bit << (j - 64);
                }
            }
        } else {
            // lanes = K-subspace; sweep queries i; c = prefix parity of keys
            // in this lane's class; result_i = parity over lanes of c & sign.
            unsigned c = 0;
            for (int s8 = 0; s8 < 16; ++s8) {
                uint4 uq = *(const uint4*)&aqsig[h][s8 * 8];
                uint4 uk = *(const uint4*)&aksig[h][s8 * 8];
                #pragma unroll
                for (int t = 0; t < 8; ++t) {
                    int i = s8 * 8 + t;
                    unsigned cwk = ((const unsigned*)&uk)[t >> 1];
                    unsigned cwq = ((const unsigned*)&uq)[t >> 1];
                    unsigned akv = (cwk >> ((t & 1) * 16)) & 0xffffu;
                    unsigned aqv = (cwq >> ((t & 1) * 16)) & 0xffffu;
                    c ^= (unsigned)(lv && (spv == akv));      // include key j=i
                    unsigned sb = bt[aqv ^ spv];
                    unsigned long long mb = __ballot((c & sb & 1u) != 0u);
                    unsigned long long bit = (unsigned long long)
                        (__popcll(mb & vmask) & 1ull);
                    if (i < 64) rlo |= bit << i; else rhi |= bit << (i - 64);
                }
            }
        }
    } else {
        // P fallback: lane = key j (and j+64); sweep queries i directly.
        const unsigned ak0 = aksig[h][lane];
        const unsigned ak1 = aksig[h][lane + 64];
        for (int s8 = 0; s8 < 16; ++s8) {
            uint4 uq = *(const uint4*)&aqsig[h][s8 * 8];
            #pragma unroll
            for (int t = 0; t < 8; ++t) {
                int i = s8 * 8 + t;
                unsigned cwq = ((const unsigned*)&uq)[t >> 1];
                unsigned aqv = (cwq >> ((t & 1) * 16)) & 0xffffu;
                unsigned ap0 = apsig[h][(i - lane) & 127];
                unsigned v0  = bt[aqv ^ ak0 ^ ap0];
                unsigned long long m0 = __ballot((v0 & 1u) != 0u);
                unsigned long long pre0 =
                    (i >= 63) ? ~0ull : ((2ull << i) - 1ull);
                unsigned cnt = (unsigned)__popcll(m0 & pre0);
                if (i >= 64) {
                    unsigned ap1 = apsig[h][(i - lane - 64) & 127];
                    unsigned v1  = bt[aqv ^ ak1 ^ ap1];
                    unsigned long long m1 = __ballot((v1 & 1u) != 0u);
                    unsigned long long pre1 =
                        (i >= 127) ? ~0ull : ((2ull << (i - 64)) - 1ull);
                    cnt += (unsigned)__popcll(m1 & pre1);
                }
                unsigned long long bit = cnt & 1u;
                if (i < 64) rlo |= bit << i; else rhi |= bit << (i - 64);
            }
        }
    }

    if (lane == 0) {
        parts[h][0] = (unsigned)rlo;
        parts[h][1] = (unsigned)(rlo >> 32);
        parts[h][2] = (unsigned)rhi;
        parts[h][3] = (unsigned)(rhi >> 32);
    }
    __syncthreads();   // barrier #2: parts visible

    // ---- majority vote across 16 heads ----
    if (tid < S) {
        int i = tid, tot = 0;
        #pragma unroll
        for (int hh = 0; hh < H; ++hh)
            tot += (parts[hh][i >> 5] >> (i & 31)) & 1;
        out[i * B + n] = (tot > (H / 2)) ? 1 : 0;
    }
}

extern "C" void kernel_launch(void* const* d_in, const int* in_sizes, int n_in,
                              void* d_out, int out_size, void* d_ws, size_t ws_size,
                              hipStream_t stream) {
    const int*   tokens      = (const int*)d_in[0];
    const float* memory      = (const float*)d_in[1];
    const int*   connections = (const int*)d_in[2];
    int*         out         = (int*)d_out;
    (void)in_sizes; (void)n_in; (void)out_size; (void)d_ws; (void)ws_size;

    softram_kernel<<<B, 1024, 0, stream>>>(tokens, memory, connections, out);
}